// Round 4
// baseline (958.460 us; speedup 1.0000x reference)
//
#include <hip/hip_runtime.h>

typedef __attribute__((ext_vector_type(8))) short short8;
typedef __attribute__((ext_vector_type(4))) float floatx4;
typedef __attribute__((ext_vector_type(2))) unsigned int uintx2;
typedef __attribute__((ext_vector_type(4))) unsigned int uintx4;

#define MFMA(a, b, c) __builtin_amdgcn_mfma_f32_16x16x32_bf16((a), (b), (c), 0, 0, 0)

__device__ __forceinline__ unsigned short f2bf(float f) {
  unsigned int u = __builtin_bit_cast(unsigned int, f);
  u += ((u >> 16) & 1u) + 0x7fffu;
  return (unsigned short)(u >> 16);
}

__device__ __forceinline__ float softplus_f(float v) {
  float a = __builtin_fabsf(v);
  float e = __expf(-a);
  float l = __logf(1.0f + e);
  return __builtin_fmaxf(v, 0.0f) + l;
}

__device__ __forceinline__ unsigned int pack_sp(float lo, float hi) {
  return (unsigned int)f2bf(softplus_f(lo)) | ((unsigned int)f2bf(softplus_f(hi)) << 16);
}

// 8B-granularity swizzle: two b64 reads per 8-elem fragment.
__device__ __forceinline__ short8 lds8(const unsigned short* s, int m, int k, int SE) {
  const int sw = (m & 15) << 2;
  const int e = m * SE + k;
  uintx2 lo = *(const uintx2*)(s + (e ^ sw));
  uintx2 hi = *(const uintx2*)(s + ((e + 4) ^ sw));
  uintx4 w;
  w.x = lo.x; w.y = lo.y; w.z = hi.x; w.w = hi.y;
  return __builtin_bit_cast(short8, w);
}

__device__ __forceinline__ void lds_st4(unsigned short* s, int m, int n, int SE, unsigned int w0,
                                        unsigned int w1) {
  const int e = (m * SE + n) ^ ((m & 15) << 2);
  uintx2 pk; pk.x = w0; pk.y = w1;
  *(uintx2*)(s + e) = pk;
}

// out[n*K + k] = bf16(in[k*N + n]); in is K x N row-major fp32
__global__ void transpose_cvt(const float* __restrict__ in, unsigned short* __restrict__ out,
                              int K, int N) {
  __shared__ float tile[32][33];
  const int bn = blockIdx.x * 32, bk = blockIdx.y * 32;
  const int tx = threadIdx.x, ty = threadIdx.y;  // 32 x 8
#pragma unroll
  for (int i = 0; i < 32; i += 8)
    tile[ty + i][tx] = in[(size_t)(bk + ty + i) * N + bn + tx];
  __syncthreads();
#pragma unroll
  for (int i = 0; i < 32; i += 8)
    out[(size_t)(bn + ty + i) * K + bk + tx] = f2bf(tile[tx][ty + i]);
}

// Fused MLP, transposed MFMA formulation: D[n][m] = sum_k Wt[n][k] * act[m][k].
// 16 waves (4/SIMD) per 64-row block for TLP; per-wave state <=128 VGPR so
// one 1024-thread block fits at 16 waves/CU. No manual prefetch: 4-wave TLP
// covers LDS/L2 latency.
__global__ __launch_bounds__(1024, 4) void mlp3(const float* __restrict__ x,
                                                const unsigned short* __restrict__ w1t,
                                                const unsigned short* __restrict__ w2t,
                                                const unsigned short* __restrict__ w3t,
                                                float* __restrict__ out) {
  __shared__ unsigned short h1s[64 * 1024];  // 128 KB: h1[m][n1] for G1/G2, h2[m][n2] for G3
  __shared__ unsigned short xs[64 * 256];    // 32 KB: x[m][k] bf16

  const int tid = threadIdx.x;
  const int lane = tid & 63;
  const int wv = tid >> 6;   // 0..15
  const int l15 = lane & 15;
  const int g = lane >> 4;   // 0..3
  const size_t m0 = (size_t)blockIdx.x * 64;

  const floatx4 z4 = {0.f, 0.f, 0.f, 0.f};

  // ---- stage x tile: 64x256 fp32 -> bf16 LDS ----
  {
    const float* xp = x + m0 * 256;
#pragma unroll
    for (int r = 0; r < 4; ++r) {
      int idx4 = r * 1024 + tid;
      int m = idx4 >> 6;
      int k = (idx4 & 63) << 2;
      floatx4 v = *(const floatx4*)(xp + m * 256 + k);
      lds_st4(xs, m, k, 256,
              (unsigned int)f2bf(v.x) | ((unsigned int)f2bf(v.y) << 16),
              (unsigned int)f2bf(v.z) | ((unsigned int)f2bf(v.w) << 16));
    }
  }
  __syncthreads();

  // ---- G1: h1 = softplus(x @ W1); wave owns 64 n1-cols; 8 k-steps ----
  {
    floatx4 acc1[4][4];
#pragma unroll
    for (int t = 0; t < 4; ++t)
#pragma unroll
      for (int mt = 0; mt < 4; ++mt) acc1[t][mt] = z4;

    const unsigned short* pA = w1t + (size_t)(wv * 64 + l15) * 256;
#pragma unroll 1
    for (int ks = 0; ks < 8; ++ks) {
      const int k = ks * 32 + g * 8;
      short8 a0 = *(const short8*)(pA + 0 * 4096 + k);
      short8 a1 = *(const short8*)(pA + 1 * 4096 + k);
      short8 a2 = *(const short8*)(pA + 2 * 4096 + k);
      short8 a3 = *(const short8*)(pA + 3 * 4096 + k);
      short8 b0 = lds8(xs, 0 * 16 + l15, k, 256);
      short8 b1 = lds8(xs, 1 * 16 + l15, k, 256);
      short8 b2 = lds8(xs, 2 * 16 + l15, k, 256);
      short8 b3 = lds8(xs, 3 * 16 + l15, k, 256);
      __builtin_amdgcn_s_setprio(1);
      acc1[0][0] = MFMA(a0, b0, acc1[0][0]);
      acc1[0][1] = MFMA(a0, b1, acc1[0][1]);
      acc1[0][2] = MFMA(a0, b2, acc1[0][2]);
      acc1[0][3] = MFMA(a0, b3, acc1[0][3]);
      acc1[1][0] = MFMA(a1, b0, acc1[1][0]);
      acc1[1][1] = MFMA(a1, b1, acc1[1][1]);
      acc1[1][2] = MFMA(a1, b2, acc1[1][2]);
      acc1[1][3] = MFMA(a1, b3, acc1[1][3]);
      acc1[2][0] = MFMA(a2, b0, acc1[2][0]);
      acc1[2][1] = MFMA(a2, b1, acc1[2][1]);
      acc1[2][2] = MFMA(a2, b2, acc1[2][2]);
      acc1[2][3] = MFMA(a2, b3, acc1[2][3]);
      acc1[3][0] = MFMA(a3, b0, acc1[3][0]);
      acc1[3][1] = MFMA(a3, b1, acc1[3][1]);
      acc1[3][2] = MFMA(a3, b2, acc1[3][2]);
      acc1[3][3] = MFMA(a3, b3, acc1[3][3]);
      __builtin_amdgcn_s_setprio(0);
    }
    // epilogue: softplus -> h1s[m][n1]
#pragma unroll
    for (int t = 0; t < 4; ++t)
#pragma unroll
      for (int mt = 0; mt < 4; ++mt) {
        const int n1 = wv * 64 + t * 16 + g * 4;
        const int m = mt * 16 + l15;
        lds_st4(h1s, m, n1, 1024, pack_sp(acc1[t][mt].x, acc1[t][mt].y),
                pack_sp(acc1[t][mt].z, acc1[t][mt].w));
      }
  }
  __syncthreads();

  // ---- G2: h2 = softplus(h1 @ W2); wave owns 64 n2-cols; 32 k-steps ----
  {
    floatx4 acc2[4][4];
#pragma unroll
    for (int t = 0; t < 4; ++t)
#pragma unroll
      for (int mt = 0; mt < 4; ++mt) acc2[t][mt] = z4;

    const unsigned short* pA = w2t + (size_t)(wv * 64 + l15) * 1024;
#pragma unroll 1
    for (int ks = 0; ks < 32; ++ks) {
      const int k = ks * 32 + g * 8;
      short8 a0 = *(const short8*)(pA + 0 * 16384 + k);
      short8 a1 = *(const short8*)(pA + 1 * 16384 + k);
      short8 a2 = *(const short8*)(pA + 2 * 16384 + k);
      short8 a3 = *(const short8*)(pA + 3 * 16384 + k);
      short8 b0 = lds8(h1s, 0 * 16 + l15, k, 1024);
      short8 b1 = lds8(h1s, 1 * 16 + l15, k, 1024);
      short8 b2 = lds8(h1s, 2 * 16 + l15, k, 1024);
      short8 b3 = lds8(h1s, 3 * 16 + l15, k, 1024);
      __builtin_amdgcn_s_setprio(1);
      acc2[0][0] = MFMA(a0, b0, acc2[0][0]);
      acc2[0][1] = MFMA(a0, b1, acc2[0][1]);
      acc2[0][2] = MFMA(a0, b2, acc2[0][2]);
      acc2[0][3] = MFMA(a0, b3, acc2[0][3]);
      acc2[1][0] = MFMA(a1, b0, acc2[1][0]);
      acc2[1][1] = MFMA(a1, b1, acc2[1][1]);
      acc2[1][2] = MFMA(a1, b2, acc2[1][2]);
      acc2[1][3] = MFMA(a1, b3, acc2[1][3]);
      acc2[2][0] = MFMA(a2, b0, acc2[2][0]);
      acc2[2][1] = MFMA(a2, b1, acc2[2][1]);
      acc2[2][2] = MFMA(a2, b2, acc2[2][2]);
      acc2[2][3] = MFMA(a2, b3, acc2[2][3]);
      acc2[3][0] = MFMA(a3, b0, acc2[3][0]);
      acc2[3][1] = MFMA(a3, b1, acc2[3][1]);
      acc2[3][2] = MFMA(a3, b2, acc2[3][2]);
      acc2[3][3] = MFMA(a3, b3, acc2[3][3]);
      __builtin_amdgcn_s_setprio(0);
    }
    __syncthreads();  // all h1 reads complete before overwrite with h2
#pragma unroll
    for (int t = 0; t < 4; ++t)
#pragma unroll
      for (int mt = 0; mt < 4; ++mt) {
        const int n2 = wv * 64 + t * 16 + g * 4;
        const int m = mt * 16 + l15;
        lds_st4(h1s, m, n2, 1024, pack_sp(acc2[t][mt].x, acc2[t][mt].y),
                pack_sp(acc2[t][mt].z, acc2[t][mt].w));
      }
  }
  __syncthreads();

  // ---- G3: out = h2 @ W3; waves split 2 m-groups x 8 n-groups; 32 k-steps ----
  {
    const int mi = wv >> 3;   // 0..1 -> m-range 32
    const int ni = wv & 7;    // 0..7 -> n3-range 32
    floatx4 acc3[2][2];       // [t(n)][u(m)]
#pragma unroll
    for (int t = 0; t < 2; ++t)
#pragma unroll
      for (int u = 0; u < 2; ++u) acc3[t][u] = z4;

    const unsigned short* pA = w3t + (size_t)(ni * 32 + l15) * 1024;
#pragma unroll 1
    for (int ks = 0; ks < 32; ++ks) {
      const int k = ks * 32 + g * 8;
      short8 a0 = *(const short8*)(pA + 0 * 16384 + k);
      short8 a1 = *(const short8*)(pA + 1 * 16384 + k);
      short8 b0 = lds8(h1s, mi * 32 + 0 * 16 + l15, k, 1024);
      short8 b1 = lds8(h1s, mi * 32 + 1 * 16 + l15, k, 1024);
      __builtin_amdgcn_s_setprio(1);
      acc3[0][0] = MFMA(a0, b0, acc3[0][0]);
      acc3[0][1] = MFMA(a0, b1, acc3[0][1]);
      acc3[1][0] = MFMA(a1, b0, acc3[1][0]);
      acc3[1][1] = MFMA(a1, b1, acc3[1][1]);
      __builtin_amdgcn_s_setprio(0);
    }
    // store out[m][n3] fp32
#pragma unroll
    for (int t = 0; t < 2; ++t)
#pragma unroll
      for (int u = 0; u < 2; ++u) {
        const int n3 = ni * 32 + t * 16 + g * 4;
        const int m = mi * 32 + u * 16 + l15;
        *(floatx4*)(out + (m0 + m) * 256 + n3) = acc3[t][u];
      }
  }
}

extern "C" void kernel_launch(void* const* d_in, const int* in_sizes, int n_in,
                              void* d_out, int out_size, void* d_ws, size_t ws_size,
                              hipStream_t stream) {
  const float* x = (const float*)d_in[0];
  const float* w1 = (const float*)d_in[1];
  const float* w2 = (const float*)d_in[2];
  const float* w3 = (const float*)d_in[3];
  float* out = (float*)d_out;

  unsigned short* w1t = (unsigned short*)d_ws;            // [1024][256]  bf16, 512 KB
  unsigned short* w2t = w1t + 1024 * 256;                 // [1024][1024] bf16, 2 MB
  unsigned short* w3t = w2t + 1024 * 1024;                // [256][1024]  bf16, 512 KB

  dim3 tb(32, 8);
  transpose_cvt<<<dim3(1024 / 32, 256 / 32), tb, 0, stream>>>(w1, w1t, 256, 1024);
  transpose_cvt<<<dim3(1024 / 32, 1024 / 32), tb, 0, stream>>>(w2, w2t, 1024, 1024);
  transpose_cvt<<<dim3(256 / 32, 1024 / 32), tb, 0, stream>>>(w3, w3t, 1024, 256);

  mlp3<<<131072 / 64, 1024, 0, stream>>>(x, w1t, w2t, w3t, out);
}

// Round 5
// 859.314 us; speedup vs baseline: 1.1154x; 1.1154x over previous
//
#include <hip/hip_runtime.h>

typedef __attribute__((ext_vector_type(8))) short short8;
typedef __attribute__((ext_vector_type(4))) float floatx4;
typedef __attribute__((ext_vector_type(2))) unsigned int uintx2;
typedef __attribute__((ext_vector_type(4))) unsigned int uintx4;
typedef unsigned short u16;

#define MFMA(a, b, c) __builtin_amdgcn_mfma_f32_16x16x32_bf16((a), (b), (c), 0, 0, 0)

__device__ __forceinline__ u16 f2bf(float f) {
  unsigned int u = __builtin_bit_cast(unsigned int, f);
  u += ((u >> 16) & 1u) + 0x7fffu;
  return (u16)(u >> 16);
}

__device__ __forceinline__ float softplus_f(float v) {
  float a = __builtin_fabsf(v);
  float e = __expf(-a);
  float l = __logf(1.0f + e);
  return __builtin_fmaxf(v, 0.0f) + l;
}

__device__ __forceinline__ unsigned int pack_sp(float lo, float hi) {
  return (unsigned int)f2bf(softplus_f(lo)) | ((unsigned int)f2bf(softplus_f(hi)) << 16);
}

// out[n*K + k] = bf16(in[k*N + n]); in is K x N row-major fp32
__global__ void transpose_cvt(const float* __restrict__ in, u16* __restrict__ out, int K, int N) {
  __shared__ float tile[32][33];
  const int bn = blockIdx.x * 32, bk = blockIdx.y * 32;
  const int tx = threadIdx.x, ty = threadIdx.y;  // 32 x 8
#pragma unroll
  for (int i = 0; i < 32; i += 8)
    tile[ty + i][tx] = in[(size_t)(bk + ty + i) * N + bn + tx];
  __syncthreads();
#pragma unroll
  for (int i = 0; i < 32; i += 8)
    out[(size_t)(bn + ty + i) * K + bk + tx] = f2bf(tile[tx][ty + i]);
}

// fp32 -> bf16, 8 elements per thread-iter
__global__ void cvt_bf16_kernel(const float* __restrict__ in, u16* __restrict__ out, long n8) {
  long i = (long)blockIdx.x * blockDim.x + threadIdx.x;
  const long stride = (long)gridDim.x * blockDim.x;
  for (; i < n8; i += stride) {
    floatx4 a = ((const floatx4*)in)[2 * i], b = ((const floatx4*)in)[2 * i + 1];
    uintx4 o;
    o.x = (unsigned)f2bf(a.x) | ((unsigned)f2bf(a.y) << 16);
    o.y = (unsigned)f2bf(a.z) | ((unsigned)f2bf(a.w) << 16);
    o.z = (unsigned)f2bf(b.x) | ((unsigned)f2bf(b.y) << 16);
    o.w = (unsigned)f2bf(b.z) | ((unsigned)f2bf(b.w) << 16);
    ((uintx4*)out)[i] = o;
  }
}

// ---------------- 8-phase 256x256 GEMM (C = act @ wt^T, wt is [N][K]) ----------------
// Half-tile = [256 rows][32 k] bf16 = 16KB, stored as permuted 16B granules:
// granule (r, g): elements [r][g*8..g*8+8) placed at granule index f = r*4 + (g ^ (r&3)).
// Fragment read (row r, chunk g=lane>>4) = ds_read_b128 at f*16B: conflict-free
// (derivation: the 8 lanes sharing each 16B bank-span land in 8 distinct 128B rounds).
// Staged via global_load_lds (linear LDS dest, per-lane pre-permuted global source).

__device__ __forceinline__ void gld16(const void* g, void* l) {
  __builtin_amdgcn_global_load_lds((const __attribute__((address_space(1))) void*)g,
                                   (__attribute__((address_space(3))) void*)l, 16, 0, 0);
}

__device__ __forceinline__ void stage_half(const u16* __restrict__ gsrc, size_t row0, int K,
                                           int kof, u16* halfp, int wv, int lane) {
#pragma unroll
  for (int j = 0; j < 2; ++j) {
    const int G = (wv * 2 + j) * 64 + lane;  // granule position this lane fills
    const int r = G >> 2;
    const int g = (G & 3) ^ (r & 3);         // granule stored here is (r, g)
    gld16(gsrc + (row0 + (size_t)r) * K + kof + g * 8, halfp + (wv * 2 + j) * 512);
  }
}

__device__ __forceinline__ short8 rdfrag(const u16* half_, int r, int g) {
  return *(const short8*)(half_ + (r * 4 + (g ^ (r & 3))) * 8);
}

// Phase: read frags -> issue 1 half-tile stage -> [vmcnt(8)] -> barrier -> 16 MFMA -> barrier.
// Staging rotation (slot s dies one phase before it is restaged; vmcnt(8) at odd phases
// retires exactly the 2 halves the upcoming phases need; never drains to 0).
#define PHASE(B, KH, NH, FRESH, STOP, STKH, STBUF, STTILE, DOVM)                              \
  {                                                                                           \
    if (FRESH) {                                                                              \
      _Pragma("unroll") for (int mt = 0; mt < 8; ++mt)                                        \
          bf[mt] = rdfrag(&lds[B][0][KH][0], wvm * 128 + mt * 16 + l15, g);                   \
    }                                                                                         \
    af[0] = rdfrag(&lds[B][1][KH][0], wvn * 64 + (NH)*32 + l15, g);                           \
    af[1] = rdfrag(&lds[B][1][KH][0], wvn * 64 + (NH)*32 + 16 + l15, g);                      \
    if ((STOP) == 0)                                                                          \
      stage_half(act, am0, K, (STTILE)*64 + (STKH)*32, &lds[STBUF][0][STKH][0], wv, lane);    \
    else                                                                                      \
      stage_half(wt, wn0, K, (STTILE)*64 + (STKH)*32, &lds[STBUF][1][STKH][0], wv, lane);     \
    if (DOVM) asm volatile("s_waitcnt vmcnt(8)" ::: "memory");                                \
    asm volatile("" ::: "memory");                                                            \
    __builtin_amdgcn_s_barrier();                                                             \
    asm volatile("" ::: "memory");                                                            \
    __builtin_amdgcn_s_setprio(1);                                                            \
    _Pragma("unroll") for (int mt = 0; mt < 8; ++mt) {                                        \
      acc[(NH)*2 + 0][mt] = MFMA(af[0], bf[mt], acc[(NH)*2 + 0][mt]);                         \
      acc[(NH)*2 + 1][mt] = MFMA(af[1], bf[mt], acc[(NH)*2 + 1][mt]);                         \
    }                                                                                         \
    __builtin_amdgcn_s_setprio(0);                                                            \
    asm volatile("" ::: "memory");                                                            \
    __builtin_amdgcn_s_barrier();                                                             \
    asm volatile("" ::: "memory");                                                            \
  }

template <int K, int EPI>  // EPI 0: softplus -> bf16 C; 1: fp32 C
__global__ __launch_bounds__(512, 2) void gemm8p(const u16* __restrict__ act,
                                                 const u16* __restrict__ wt,
                                                 void* __restrict__ Cout, int N, int nbn) {
  __shared__ u16 lds[2][2][2][8192];  // [buf][op 0=ACT 1=W][khalf][16KB]
  const int tid = threadIdx.x, lane = tid & 63, wv = tid >> 6;
  const int l15 = lane & 15, g = lane >> 4;
  const int wvm = wv >> 2, wvn = wv & 3;  // 2 x 4 wave grid; wave owns 128m x 64n
  const int nwg = gridDim.x, o = blockIdx.x;
  const int sw = (o & 7) * (nwg >> 3) + (o >> 3);  // XCD-contiguous chunks
  const int bm = sw / nbn, bn = sw % nbn;
  const size_t am0 = (size_t)bm * 256;
  const size_t wn0 = (size_t)bn * 256;
  constexpr int NT = K / 64, NIT = NT / 2;

  floatx4 acc[4][8];
  const floatx4 z4 = {0.f, 0.f, 0.f, 0.f};
#pragma unroll
  for (int t = 0; t < 4; ++t)
#pragma unroll
    for (int mt = 0; mt < 8; ++mt) acc[t][mt] = z4;

  // prologue: T0 (all 4 halves) + T1 (kh0 halves)
  stage_half(act, am0, K, 0, &lds[0][0][0][0], wv, lane);
  stage_half(wt, wn0, K, 0, &lds[0][1][0][0], wv, lane);
  stage_half(act, am0, K, 32, &lds[0][0][1][0], wv, lane);
  stage_half(wt, wn0, K, 32, &lds[0][1][1][0], wv, lane);
  stage_half(act, am0, K, 64, &lds[1][0][0][0], wv, lane);
  stage_half(wt, wn0, K, 64, &lds[1][1][0][0], wv, lane);
  asm volatile("s_waitcnt vmcnt(0)" ::: "memory");
  __builtin_amdgcn_s_barrier();
  asm volatile("" ::: "memory");

  short8 bf[8], af[2];
#pragma unroll 1
  for (int it = 0; it < NIT; ++it) {
    const int s01 = 2 * it + 1;
    const int s25 = (2 * it + 2 < NT - 1) ? 2 * it + 2 : NT - 1;
    const int s67 = (2 * it + 3 < NT - 1) ? 2 * it + 3 : NT - 1;
    PHASE(0, 0, 0, true,  0, 1, 1, s01, false)  // stage (2it+1).ACT.kh1
    PHASE(0, 0, 1, false, 1, 1, 1, s01, true)   // stage (2it+1).W.kh1
    PHASE(0, 1, 0, true,  0, 0, 0, s25, false)  // stage (2it+2).ACT.kh0
    PHASE(0, 1, 1, false, 1, 0, 0, s25, true)   // stage (2it+2).W.kh0
    PHASE(1, 0, 0, true,  0, 1, 0, s25, false)  // stage (2it+2).ACT.kh1
    PHASE(1, 0, 1, false, 1, 1, 0, s25, true)   // stage (2it+2).W.kh1
    PHASE(1, 1, 0, true,  0, 0, 1, s67, false)  // stage (2it+3).ACT.kh0
    PHASE(1, 1, 1, false, 1, 0, 1, s67, true)   // stage (2it+3).W.kh0
  }

  // epilogue: D[n][m] frags -> C[m][n]
#pragma unroll
  for (int t = 0; t < 4; ++t)
#pragma unroll
    for (int mt = 0; mt < 8; ++mt) {
      const size_t m = am0 + wvm * 128 + mt * 16 + l15;
      const int n = (int)wn0 + wvn * 64 + t * 16 + g * 4;
      if (EPI == 0) {
        uintx2 pk;
        pk.x = pack_sp(acc[t][mt].x, acc[t][mt].y);
        pk.y = pack_sp(acc[t][mt].z, acc[t][mt].w);
        *(uintx2*)((u16*)Cout + m * N + n) = pk;
      } else {
        *(floatx4*)((float*)Cout + m * N + n) = acc[t][mt];
      }
    }
}

// ---------------- fallback: R1 fused kernel (used only if ws is too small) ----------------
__global__ __launch_bounds__(512, 2) void mlp3_fused(const float* __restrict__ x,
                                                     const u16* __restrict__ w1t,
                                                     const u16* __restrict__ w2t,
                                                     const u16* __restrict__ w3t,
                                                     float* __restrict__ out) {
  __shared__ u16 h1s[64 * 1024];
  __shared__ u16 xs[64 * 256];
  const int tid = threadIdx.x, lane = tid & 63, wv = tid >> 6;
  const int l15 = lane & 15, g = lane >> 4;
  const size_t m0 = (size_t)blockIdx.x * 64;
  const floatx4 z4 = {0.f, 0.f, 0.f, 0.f};
  {
    const float* xp = x + m0 * 256;
#pragma unroll
    for (int r = 0; r < 8; ++r) {
      int idx4 = r * 512 + tid;
      int m = idx4 >> 6, k = (idx4 & 63) << 2;
      floatx4 v = *(const floatx4*)(xp + m * 256 + k);
      uintx2 pk;
      pk.x = (unsigned)f2bf(v.x) | ((unsigned)f2bf(v.y) << 16);
      pk.y = (unsigned)f2bf(v.z) | ((unsigned)f2bf(v.w) << 16);
      *(uintx2*)(xs + ((m * 256 + k) ^ ((m & 7) << 3))) = pk;
    }
  }
  __syncthreads();
#pragma unroll 1
  for (int c = 0; c < 4; ++c) {
    floatx4 acc[2][4];
#pragma unroll
    for (int t = 0; t < 2; ++t)
#pragma unroll
      for (int mt = 0; mt < 4; ++mt) acc[t][mt] = z4;
    const u16* p0 = w1t + (size_t)(c * 256 + wv * 32 + l15) * 256;
#pragma unroll
    for (int ks = 0; ks < 8; ++ks) {
      const int k = ks * 32 + g * 8;
      short8 a0 = *(const short8*)(p0 + k);
      short8 a1 = *(const short8*)(p0 + 16 * 256 + k);
      short8 b0 = *(const short8*)(xs + (((0 * 16 + l15) * 256 + k) ^ ((l15 & 7) << 3)));
      short8 b1 = *(const short8*)(xs + (((1 * 16 + l15) * 256 + k) ^ ((l15 & 7) << 3)));
      short8 b2 = *(const short8*)(xs + (((2 * 16 + l15) * 256 + k) ^ ((l15 & 7) << 3)));
      short8 b3 = *(const short8*)(xs + (((3 * 16 + l15) * 256 + k) ^ ((l15 & 7) << 3)));
      acc[0][0] = MFMA(a0, b0, acc[0][0]); acc[0][1] = MFMA(a0, b1, acc[0][1]);
      acc[0][2] = MFMA(a0, b2, acc[0][2]); acc[0][3] = MFMA(a0, b3, acc[0][3]);
      acc[1][0] = MFMA(a1, b0, acc[1][0]); acc[1][1] = MFMA(a1, b1, acc[1][1]);
      acc[1][2] = MFMA(a1, b2, acc[1][2]); acc[1][3] = MFMA(a1, b3, acc[1][3]);
    }
#pragma unroll
    for (int t = 0; t < 2; ++t)
#pragma unroll
      for (int mt = 0; mt < 4; ++mt) {
        const int n1 = c * 256 + wv * 32 + t * 16 + g * 4;
        const int m = mt * 16 + l15;
        uintx2 pk;
        pk.x = pack_sp(acc[t][mt].x, acc[t][mt].y);
        pk.y = pack_sp(acc[t][mt].z, acc[t][mt].w);
        *(uintx2*)(h1s + ((m * 1024 + n1) ^ ((m & 7) << 3))) = pk;
      }
  }
  __syncthreads();
  floatx4 acc3[2][4];
#pragma unroll
  for (int t = 0; t < 2; ++t)
#pragma unroll
    for (int mt = 0; mt < 4; ++mt) acc3[t][mt] = z4;
#pragma unroll 1
  for (int c2 = 0; c2 < 4; ++c2) {
    floatx4 acc2[2][4];
#pragma unroll
    for (int t = 0; t < 2; ++t)
#pragma unroll
      for (int mt = 0; mt < 4; ++mt) acc2[t][mt] = z4;
    {
      const u16* p0 = w2t + (size_t)(c2 * 256 + wv * 32 + l15) * 1024;
#pragma unroll 4
      for (int ks = 0; ks < 32; ++ks) {
        const int k = ks * 32 + g * 8;
        short8 a0 = *(const short8*)(p0 + k);
        short8 a1 = *(const short8*)(p0 + 16 * 1024 + k);
        short8 b0 = *(const short8*)(h1s + (((0 * 16 + l15) * 1024 + k) ^ ((l15 & 7) << 3)));
        short8 b1 = *(const short8*)(h1s + (((1 * 16 + l15) * 1024 + k) ^ ((l15 & 7) << 3)));
        short8 b2 = *(const short8*)(h1s + (((2 * 16 + l15) * 1024 + k) ^ ((l15 & 7) << 3)));
        short8 b3 = *(const short8*)(h1s + (((3 * 16 + l15) * 1024 + k) ^ ((l15 & 7) << 3)));
        acc2[0][0] = MFMA(a0, b0, acc2[0][0]); acc2[0][1] = MFMA(a0, b1, acc2[0][1]);
        acc2[0][2] = MFMA(a0, b2, acc2[0][2]); acc2[0][3] = MFMA(a0, b3, acc2[0][3]);
        acc2[1][0] = MFMA(a1, b0, acc2[1][0]); acc2[1][1] = MFMA(a1, b1, acc2[1][1]);
        acc2[1][2] = MFMA(a1, b2, acc2[1][2]); acc2[1][3] = MFMA(a1, b3, acc2[1][3]);
      }
    }
    __syncthreads();
#pragma unroll
    for (int t = 0; t < 2; ++t)
#pragma unroll
      for (int mt = 0; mt < 4; ++mt) {
        const int n2l = wv * 32 + t * 16 + g * 4;
        const int m = mt * 16 + l15;
        uintx2 pk;
        pk.x = pack_sp(acc2[t][mt].x, acc2[t][mt].y);
        pk.y = pack_sp(acc2[t][mt].z, acc2[t][mt].w);
        *(uintx2*)(xs + ((m * 256 + n2l) ^ ((m & 7) << 3))) = pk;
      }
    __syncthreads();
    {
      const u16* p0 = w3t + (size_t)(wv * 32 + l15) * 1024 + c2 * 256;
#pragma unroll
      for (int ks = 0; ks < 8; ++ks) {
        const int k = ks * 32 + g * 8;
        short8 a0 = *(const short8*)(p0 + k);
        short8 a1 = *(const short8*)(p0 + 16 * 1024 + k);
        short8 b0 = *(const short8*)(xs + (((0 * 16 + l15) * 256 + k) ^ ((l15 & 7) << 3)));
        short8 b1 = *(const short8*)(xs + (((1 * 16 + l15) * 256 + k) ^ ((l15 & 7) << 3)));
        short8 b2 = *(const short8*)(xs + (((2 * 16 + l15) * 256 + k) ^ ((l15 & 7) << 3)));
        short8 b3 = *(const short8*)(xs + (((3 * 16 + l15) * 256 + k) ^ ((l15 & 7) << 3)));
        acc3[0][0] = MFMA(a0, b0, acc3[0][0]); acc3[0][1] = MFMA(a0, b1, acc3[0][1]);
        acc3[0][2] = MFMA(a0, b2, acc3[0][2]); acc3[0][3] = MFMA(a0, b3, acc3[0][3]);
        acc3[1][0] = MFMA(a1, b0, acc3[1][0]); acc3[1][1] = MFMA(a1, b1, acc3[1][1]);
        acc3[1][2] = MFMA(a1, b2, acc3[1][2]); acc3[1][3] = MFMA(a1, b3, acc3[1][3]);
      }
    }
  }
#pragma unroll
  for (int t = 0; t < 2; ++t)
#pragma unroll
    for (int mt = 0; mt < 4; ++mt) {
      const int n3 = wv * 32 + t * 16 + g * 4;
      const int m = mt * 16 + l15;
      *(floatx4*)(out + (m0 + m) * 256 + n3) = acc3[t][mt];
    }
}

extern "C" void kernel_launch(void* const* d_in, const int* in_sizes, int n_in,
                              void* d_out, int out_size, void* d_ws, size_t ws_size,
                              hipStream_t stream) {
  const float* x = (const float*)d_in[0];
  const float* w1 = (const float*)d_in[1];
  const float* w2 = (const float*)d_in[2];
  const float* w3 = (const float*)d_in[3];
  float* out = (float*)d_out;
  const size_t M = 131072;

  u16* w1t = (u16*)d_ws;                      // [1024][256]
  u16* w2t = w1t + 1024 * 256;                // [1024][1024]
  u16* w3t = w2t + 1024 * 1024;               // [256][1024]
  u16* xbf = w3t + 256 * 1024;                // [M][256]
  u16* h1 = xbf + M * 256;                    // [M][1024]
  u16* h2 = h1 + M * 1024;                    // [M][1024]
  const size_t NEED = ((size_t)(1024 * 256 + 1024 * 1024 + 256 * 1024) + M * 256 + 2 * M * 1024) * 2;

  dim3 tb(32, 8);
  transpose_cvt<<<dim3(32, 8), tb, 0, stream>>>(w1, w1t, 256, 1024);
  transpose_cvt<<<dim3(32, 32), tb, 0, stream>>>(w2, w2t, 1024, 1024);
  transpose_cvt<<<dim3(8, 32), tb, 0, stream>>>(w3, w3t, 1024, 256);

  if (ws_size >= NEED) {
    cvt_bf16_kernel<<<2048, 256, 0, stream>>>(x, xbf, (long)(M * 256 / 8));
    gemm8p<256, 0><<<2048, 512, 0, stream>>>(xbf, w1t, h1, 1024, 4);
    gemm8p<1024, 0><<<2048, 512, 0, stream>>>(h1, w2t, h2, 1024, 4);
    gemm8p<1024, 1><<<512, 512, 0, stream>>>(h2, w3t, out, 256, 1);
  } else {
    mlp3_fused<<<M / 64, 512, 0, stream>>>(x, w1t, w2t, w3t, out);
  }
}

// Round 6
// 702.205 us; speedup vs baseline: 1.3649x; 1.2237x over previous
//
#include <hip/hip_runtime.h>

typedef __attribute__((ext_vector_type(8))) short short8;
typedef __attribute__((ext_vector_type(4))) float floatx4;
typedef __attribute__((ext_vector_type(2))) unsigned int uintx2;
typedef __attribute__((ext_vector_type(4))) unsigned int uintx4;
typedef unsigned short u16;

#define MFMA(a, b, c) __builtin_amdgcn_mfma_f32_16x16x32_bf16((a), (b), (c), 0, 0, 0)

__device__ __forceinline__ u16 f2bf(float f) {
  unsigned int u = __builtin_bit_cast(unsigned int, f);
  u += ((u >> 16) & 1u) + 0x7fffu;
  return (u16)(u >> 16);
}

__device__ __forceinline__ float softplus_f(float v) {
  float a = __builtin_fabsf(v);
  float e = __expf(-a);
  float l = __logf(1.0f + e);
  return __builtin_fmaxf(v, 0.0f) + l;
}

__device__ __forceinline__ unsigned int pack_sp(float lo, float hi) {
  return (unsigned int)f2bf(softplus_f(lo)) | ((unsigned int)f2bf(softplus_f(hi)) << 16);
}

// out[n*K + k] = bf16(in[k*N + n]); in is K x N row-major fp32
__global__ void transpose_cvt(const float* __restrict__ in, u16* __restrict__ out, int K, int N) {
  __shared__ float tile[32][33];
  const int bn = blockIdx.x * 32, bk = blockIdx.y * 32;
  const int tx = threadIdx.x, ty = threadIdx.y;  // 32 x 8
#pragma unroll
  for (int i = 0; i < 32; i += 8)
    tile[ty + i][tx] = in[(size_t)(bk + ty + i) * N + bn + tx];
  __syncthreads();
#pragma unroll
  for (int i = 0; i < 32; i += 8)
    out[(size_t)(bn + ty + i) * K + bk + tx] = f2bf(tile[tx][ty + i]);
}

// fp32 -> bf16, 8 elements per thread-iter
__global__ void cvt_bf16_kernel(const float* __restrict__ in, u16* __restrict__ out, long n8) {
  long i = (long)blockIdx.x * blockDim.x + threadIdx.x;
  const long stride = (long)gridDim.x * blockDim.x;
  for (; i < n8; i += stride) {
    floatx4 a = ((const floatx4*)in)[2 * i], b = ((const floatx4*)in)[2 * i + 1];
    uintx4 o;
    o.x = (unsigned)f2bf(a.x) | ((unsigned)f2bf(a.y) << 16);
    o.y = (unsigned)f2bf(a.z) | ((unsigned)f2bf(a.w) << 16);
    o.z = (unsigned)f2bf(b.x) | ((unsigned)f2bf(b.y) << 16);
    o.w = (unsigned)f2bf(b.z) | ((unsigned)f2bf(b.w) << 16);
    ((uintx4*)out)[i] = o;
  }
}

// ---------------- 8-phase 256x256 GEMM (C = act @ wt^T, wt is [N][K]) ----------------
// Half-tile = [256 rows][32 k] bf16 = 16KB, stored as permuted 16B granules:
// granule (r, g): elements [r][g*8..g*8+8) at granule slot f = r*4 + (g ^ (r&3)).
// Staged via global_load_lds (linear LDS dest = wave-uniform base + lane*16,
// per-lane pre-permuted global source). Fragment read = one ds_read_b128 at
// slot f*16B; 64-lane pattern lands 8 lanes per 16B bank-span = data floor.

__device__ __forceinline__ void gld16(const void* g, void* l) {
  __builtin_amdgcn_global_load_lds((const __attribute__((address_space(1))) void*)g,
                                   (__attribute__((address_space(3))) void*)l, 16, 0, 0);
}

__device__ __forceinline__ void stage_half(const u16* __restrict__ gsrc, size_t row0, int K,
                                           int kof, u16* halfp, int wv, int lane) {
#pragma unroll
  for (int j = 0; j < 2; ++j) {
    const int G = (wv * 2 + j) * 64 + lane;  // granule slot this lane fills
    const int r = G >> 2;
    const int g = (G & 3) ^ (r & 3);         // granule stored here is (r, g)
    gld16(gsrc + (row0 + (size_t)r) * K + kof + g * 8, halfp + (wv * 2 + j) * 512);
  }
}

__device__ __forceinline__ short8 rdfrag(const u16* half_, int r, int g) {
  return *(const short8*)(half_ + (r * 4 + (g ^ (r & 3))) * 8);
}

// Phase: read frags -> issue 1 half-tile stage -> [vmcnt(8)] -> barrier -> 16 MFMA -> barrier.
// vmcnt(8) at even phases retires exactly the two halves the next two phases read;
// never drains to 0 in the main loop.
#define PHASE(B, KH, NH, FRESH, STOP, STKH, STBUF, STTILE, DOVM)                              \
  {                                                                                           \
    if (FRESH) {                                                                              \
      _Pragma("unroll") for (int mt = 0; mt < 8; ++mt)                                        \
          bf[mt] = rdfrag(&lds[B][0][KH][0], wvm * 128 + mt * 16 + l15, g);                   \
    }                                                                                         \
    af[0] = rdfrag(&lds[B][1][KH][0], wvn * 64 + (NH)*32 + l15, g);                           \
    af[1] = rdfrag(&lds[B][1][KH][0], wvn * 64 + (NH)*32 + 16 + l15, g);                      \
    if ((STOP) == 0)                                                                          \
      stage_half(act, am0, K, (STTILE)*64 + (STKH)*32, &lds[STBUF][0][STKH][0], wv, lane);    \
    else                                                                                      \
      stage_half(wt, wn0, K, (STTILE)*64 + (STKH)*32, &lds[STBUF][1][STKH][0], wv, lane);     \
    if (DOVM) asm volatile("s_waitcnt vmcnt(8)" ::: "memory");                                \
    asm volatile("" ::: "memory");                                                            \
    __builtin_amdgcn_s_barrier();                                                             \
    asm volatile("" ::: "memory");                                                            \
    __builtin_amdgcn_s_setprio(1);                                                            \
    _Pragma("unroll") for (int mt = 0; mt < 8; ++mt) {                                        \
      acc[(NH)*2 + 0][mt] = MFMA(af[0], bf[mt], acc[(NH)*2 + 0][mt]);                         \
      acc[(NH)*2 + 1][mt] = MFMA(af[1], bf[mt], acc[(NH)*2 + 1][mt]);                         \
    }                                                                                         \
    __builtin_amdgcn_s_setprio(0);                                                            \
    asm volatile("" ::: "memory");                                                            \
    __builtin_amdgcn_s_barrier();                                                             \
    asm volatile("" ::: "memory");                                                            \
  }

template <int K, int EPI>  // EPI 0: softplus -> bf16 C; 1: fp32 C
__global__ __launch_bounds__(512, 2) void gemm8p(const u16* __restrict__ act,
                                                 const u16* __restrict__ wt,
                                                 void* __restrict__ Cout, int N, int nbn) {
  __shared__ u16 lds[2][2][2][8192];  // [buf][op 0=ACT 1=W][khalf][16KB]
  const int tid = threadIdx.x, lane = tid & 63, wv = tid >> 6;
  const int l15 = lane & 15, g = lane >> 4;
  const int wvm = wv >> 2, wvn = wv & 3;  // 2 x 4 wave grid; wave owns 128m x 64n
  const int nwg = gridDim.x, o = blockIdx.x;
  const int sw = (o & 7) * (nwg >> 3) + (o >> 3);  // XCD-contiguous chunks (nwg % 8 == 0)
  const int bm = sw / nbn, bn = sw % nbn;
  const size_t am0 = (size_t)bm * 256;
  const size_t wn0 = (size_t)bn * 256;
  constexpr int NT = K / 64, NIT = NT / 2;

  floatx4 acc[4][8];
  const floatx4 z4 = {0.f, 0.f, 0.f, 0.f};
#pragma unroll
  for (int t = 0; t < 4; ++t)
#pragma unroll
    for (int mt = 0; mt < 8; ++mt) acc[t][mt] = z4;

  // prologue: T0 (all 4 halves) + T1 (kh0 halves)
  stage_half(act, am0, K, 0, &lds[0][0][0][0], wv, lane);
  stage_half(wt, wn0, K, 0, &lds[0][1][0][0], wv, lane);
  stage_half(act, am0, K, 32, &lds[0][0][1][0], wv, lane);
  stage_half(wt, wn0, K, 32, &lds[0][1][1][0], wv, lane);
  stage_half(act, am0, K, 64, &lds[1][0][0][0], wv, lane);
  stage_half(wt, wn0, K, 64, &lds[1][1][0][0], wv, lane);
  asm volatile("s_waitcnt vmcnt(0)" ::: "memory");
  __builtin_amdgcn_s_barrier();
  asm volatile("" ::: "memory");

  short8 bf[8], af[2];
#pragma unroll 1
  for (int it = 0; it < NIT; ++it) {
    const int s01 = 2 * it + 1;
    const int s25 = (2 * it + 2 < NT - 1) ? 2 * it + 2 : NT - 1;
    const int s67 = (2 * it + 3 < NT - 1) ? 2 * it + 3 : NT - 1;
    PHASE(0, 0, 0, true,  0, 1, 1, s01, false)  // stage (2it+1).ACT.kh1
    PHASE(0, 0, 1, false, 1, 1, 1, s01, true)   // stage (2it+1).W.kh1
    PHASE(0, 1, 0, true,  0, 0, 0, s25, false)  // stage (2it+2).ACT.kh0
    PHASE(0, 1, 1, false, 1, 0, 0, s25, true)   // stage (2it+2).W.kh0
    PHASE(1, 0, 0, true,  0, 1, 0, s25, false)  // stage (2it+2).ACT.kh1
    PHASE(1, 0, 1, false, 1, 1, 0, s25, true)   // stage (2it+2).W.kh1
    PHASE(1, 1, 0, true,  0, 0, 1, s67, false)  // stage (2it+3).ACT.kh0
    PHASE(1, 1, 1, false, 1, 0, 1, s67, true)   // stage (2it+3).W.kh0
  }

  // epilogue: D[n][m] frags -> C[m][n]
#pragma unroll
  for (int t = 0; t < 4; ++t)
#pragma unroll
    for (int mt = 0; mt < 8; ++mt) {
      const size_t m = am0 + wvm * 128 + mt * 16 + l15;
      const int n = (int)wn0 + wvn * 64 + t * 16 + g * 4;
      if (EPI == 0) {
        uintx2 pk;
        pk.x = pack_sp(acc[t][mt].x, acc[t][mt].y);
        pk.y = pack_sp(acc[t][mt].z, acc[t][mt].w);
        *(uintx2*)((u16*)Cout + m * N + n) = pk;
      } else {
        *(floatx4*)((float*)Cout + m * N + n) = acc[t][mt];
      }
    }
}

// ---------------- fallback: R1 fused kernel (used only if ws is too small) ----------------
__global__ __launch_bounds__(512, 2) void mlp3_fused(const float* __restrict__ x,
                                                     const u16* __restrict__ w1t,
                                                     const u16* __restrict__ w2t,
                                                     const u16* __restrict__ w3t,
                                                     float* __restrict__ out) {
  __shared__ u16 h1s[64 * 1024];
  __shared__ u16 xs[64 * 256];
  const int tid = threadIdx.x, lane = tid & 63, wv = tid >> 6;
  const int l15 = lane & 15, g = lane >> 4;
  const size_t m0 = (size_t)blockIdx.x * 64;
  const floatx4 z4 = {0.f, 0.f, 0.f, 0.f};
  {
    const float* xp = x + m0 * 256;
#pragma unroll
    for (int r = 0; r < 8; ++r) {
      int idx4 = r * 512 + tid;
      int m = idx4 >> 6, k = (idx4 & 63) << 2;
      floatx4 v = *(const floatx4*)(xp + m * 256 + k);
      uintx2 pk;
      pk.x = (unsigned)f2bf(v.x) | ((unsigned)f2bf(v.y) << 16);
      pk.y = (unsigned)f2bf(v.z) | ((unsigned)f2bf(v.w) << 16);
      *(uintx2*)(xs + ((m * 256 + k) ^ ((m & 7) << 3))) = pk;
    }
  }
  __syncthreads();
#pragma unroll 1
  for (int c = 0; c < 4; ++c) {
    floatx4 acc[2][4];
#pragma unroll
    for (int t = 0; t < 2; ++t)
#pragma unroll
      for (int mt = 0; mt < 4; ++mt) acc[t][mt] = z4;
    const u16* p0 = w1t + (size_t)(c * 256 + wv * 32 + l15) * 256;
#pragma unroll
    for (int ks = 0; ks < 8; ++ks) {
      const int k = ks * 32 + g * 8;
      short8 a0 = *(const short8*)(p0 + k);
      short8 a1 = *(const short8*)(p0 + 16 * 256 + k);
      short8 b0 = *(const short8*)(xs + (((0 * 16 + l15) * 256 + k) ^ ((l15 & 7) << 3)));
      short8 b1 = *(const short8*)(xs + (((1 * 16 + l15) * 256 + k) ^ ((l15 & 7) << 3)));
      short8 b2 = *(const short8*)(xs + (((2 * 16 + l15) * 256 + k) ^ ((l15 & 7) << 3)));
      short8 b3 = *(const short8*)(xs + (((3 * 16 + l15) * 256 + k) ^ ((l15 & 7) << 3)));
      acc[0][0] = MFMA(a0, b0, acc[0][0]); acc[0][1] = MFMA(a0, b1, acc[0][1]);
      acc[0][2] = MFMA(a0, b2, acc[0][2]); acc[0][3] = MFMA(a0, b3, acc[0][3]);
      acc[1][0] = MFMA(a1, b0, acc[1][0]); acc[1][1] = MFMA(a1, b1, acc[1][1]);
      acc[1][2] = MFMA(a1, b2, acc[1][2]); acc[1][3] = MFMA(a1, b3, acc[1][3]);
    }
#pragma unroll
    for (int t = 0; t < 2; ++t)
#pragma unroll
      for (int mt = 0; mt < 4; ++mt) {
        const int n1 = c * 256 + wv * 32 + t * 16 + g * 4;
        const int m = mt * 16 + l15;
        uintx2 pk;
        pk.x = pack_sp(acc[t][mt].x, acc[t][mt].y);
        pk.y = pack_sp(acc[t][mt].z, acc[t][mt].w);
        *(uintx2*)(h1s + ((m * 1024 + n1) ^ ((m & 7) << 3))) = pk;
      }
  }
  __syncthreads();
  floatx4 acc3[2][4];
#pragma unroll
  for (int t = 0; t < 2; ++t)
#pragma unroll
    for (int mt = 0; mt < 4; ++mt) acc3[t][mt] = z4;
#pragma unroll 1
  for (int c2 = 0; c2 < 4; ++c2) {
    floatx4 acc2[2][4];
#pragma unroll
    for (int t = 0; t < 2; ++t)
#pragma unroll
      for (int mt = 0; mt < 4; ++mt) acc2[t][mt] = z4;
    {
      const u16* p0 = w2t + (size_t)(c2 * 256 + wv * 32 + l15) * 1024;
#pragma unroll 4
      for (int ks = 0; ks < 32; ++ks) {
        const int k = ks * 32 + g * 8;
        short8 a0 = *(const short8*)(p0 + k);
        short8 a1 = *(const short8*)(p0 + 16 * 1024 + k);
        short8 b0 = *(const short8*)(h1s + (((0 * 16 + l15) * 1024 + k) ^ ((l15 & 7) << 3)));
        short8 b1 = *(const short8*)(h1s + (((1 * 16 + l15) * 1024 + k) ^ ((l15 & 7) << 3)));
        short8 b2 = *(const short8*)(h1s + (((2 * 16 + l15) * 1024 + k) ^ ((l15 & 7) << 3)));
        short8 b3 = *(const short8*)(h1s + (((3 * 16 + l15) * 1024 + k) ^ ((l15 & 7) << 3)));
        acc2[0][0] = MFMA(a0, b0, acc2[0][0]); acc2[0][1] = MFMA(a0, b1, acc2[0][1]);
        acc2[0][2] = MFMA(a0, b2, acc2[0][2]); acc2[0][3] = MFMA(a0, b3, acc2[0][3]);
        acc2[1][0] = MFMA(a1, b0, acc2[1][0]); acc2[1][1] = MFMA(a1, b1, acc2[1][1]);
        acc2[1][2] = MFMA(a1, b2, acc2[1][2]); acc2[1][3] = MFMA(a1, b3, acc2[1][3]);
      }
    }
    __syncthreads();
#pragma unroll
    for (int t = 0; t < 2; ++t)
#pragma unroll
      for (int mt = 0; mt < 4; ++mt) {
        const int n2l = wv * 32 + t * 16 + g * 4;
        const int m = mt * 16 + l15;
        uintx2 pk;
        pk.x = pack_sp(acc2[t][mt].x, acc2[t][mt].y);
        pk.y = pack_sp(acc2[t][mt].z, acc2[t][mt].w);
        *(uintx2*)(xs + ((m * 256 + n2l) ^ ((m & 7) << 3))) = pk;
      }
    __syncthreads();
    {
      const u16* p0 = w3t + (size_t)(wv * 32 + l15) * 1024 + c2 * 256;
#pragma unroll
      for (int ks = 0; ks < 8; ++ks) {
        const int k = ks * 32 + g * 8;
        short8 a0 = *(const short8*)(p0 + k);
        short8 a1 = *(const short8*)(p0 + 16 * 1024 + k);
        short8 b0 = *(const short8*)(xs + (((0 * 16 + l15) * 256 + k) ^ ((l15 & 7) << 3)));
        short8 b1 = *(const short8*)(xs + (((1 * 16 + l15) * 256 + k) ^ ((l15 & 7) << 3)));
        short8 b2 = *(const short8*)(xs + (((2 * 16 + l15) * 256 + k) ^ ((l15 & 7) << 3)));
        short8 b3 = *(const short8*)(xs + (((3 * 16 + l15) * 256 + k) ^ ((l15 & 7) << 3)));
        acc3[0][0] = MFMA(a0, b0, acc3[0][0]); acc3[0][1] = MFMA(a0, b1, acc3[0][1]);
        acc3[0][2] = MFMA(a0, b2, acc3[0][2]); acc3[0][3] = MFMA(a0, b3, acc3[0][3]);
        acc3[1][0] = MFMA(a1, b0, acc3[1][0]); acc3[1][1] = MFMA(a1, b1, acc3[1][1]);
        acc3[1][2] = MFMA(a1, b2, acc3[1][2]); acc3[1][3] = MFMA(a1, b3, acc3[1][3]);
      }
    }
  }
#pragma unroll
  for (int t = 0; t < 2; ++t)
#pragma unroll
    for (int mt = 0; mt < 4; ++mt) {
      const int n3 = wv * 32 + t * 16 + g * 4;
      const int m = mt * 16 + l15;
      *(floatx4*)(out + (m0 + m) * 256 + n3) = acc3[t][mt];
    }
}

extern "C" void kernel_launch(void* const* d_in, const int* in_sizes, int n_in,
                              void* d_out, int out_size, void* d_ws, size_t ws_size,
                              hipStream_t stream) {
  const float* x = (const float*)d_in[0];
  const float* w1 = (const float*)d_in[1];
  const float* w2 = (const float*)d_in[2];
  const float* w3 = (const float*)d_in[3];
  float* out = (float*)d_out;
  const size_t M = 131072;

  u16* w1t = (u16*)d_ws;                      // [1024][256]
  u16* w2t = w1t + 1024 * 256;                // [1024][1024]
  u16* w3t = w2t + 1024 * 1024;               // [256][1024]
  u16* bufA = w3t + 256 * 1024;               // CM*1024 bf16 (xbf in first CM*256, then h2)
  const size_t weights_el = 1024 * 256 + 1024 * 1024 + 256 * 1024;

  // largest chunk that fits: need = weights + 2 ping-pong buffers of CM*1024 bf16
  size_t CM = 0;
  const size_t cands[4] = {32768, 16384, 8192, 4096};
  for (int i = 0; i < 4; ++i) {
    size_t need = (weights_el + 2 * cands[i] * 1024) * sizeof(u16);
    if (ws_size >= need) { CM = cands[i]; break; }
  }

  dim3 tb(32, 8);
  transpose_cvt<<<dim3(32, 8), tb, 0, stream>>>(w1, w1t, 256, 1024);
  transpose_cvt<<<dim3(32, 32), tb, 0, stream>>>(w2, w2t, 1024, 1024);
  transpose_cvt<<<dim3(8, 32), tb, 0, stream>>>(w3, w3t, 1024, 256);

  if (CM) {
    u16* bufB = bufA + CM * 1024;
    const int nchunk = (int)(M / CM);
    for (int ci = 0; ci < nchunk; ++ci) {
      const float* xc = x + (size_t)ci * CM * 256;
      float* oc = out + (size_t)ci * CM * 256;
      cvt_bf16_kernel<<<1024, 256, 0, stream>>>(xc, bufA, (long)(CM * 32));
      gemm8p<256, 0><<<(int)(CM / 256) * 4, 512, 0, stream>>>(bufA, w1t, bufB, 1024, 4);
      gemm8p<1024, 0><<<(int)(CM / 256) * 4, 512, 0, stream>>>(bufB, w2t, bufA, 1024, 4);
      gemm8p<1024, 1><<<(int)(CM / 256), 512, 0, stream>>>(bufA, w3t, oc, 256, 1);
    }
  } else {
    mlp3_fused<<<M / 64, 512, 0, stream>>>(x, w1t, w2t, w3t, out);
  }
}